// Round 1
// baseline (696.026 us; speedup 1.0000x reference)
//
#include <hip/hip_runtime.h>
#include <cstdint>
#include <cstddef>

// ---------------------------------------------------------------------------
// Transformer block, MI355X bf16 MFMA implementation.
// x:[4,2048,1024] fp32. All GEMMs in bf16 via mfma_f32_16x16x32_bf16,
// fp32 accumulate. Weights converted+transposed to [N][K] bf16 each call.
// ---------------------------------------------------------------------------

typedef unsigned short u16;
typedef __attribute__((ext_vector_type(8))) __bf16 bf16x8;   // 4 VGPRs, MFMA A/B frag
typedef __attribute__((ext_vector_type(4))) float f32x4;     // MFMA C/D frag

__device__ __forceinline__ u16 f2bf(float f) {
  union { float f; unsigned int u; } c; c.f = f;
  unsigned int u = c.u;
  u += 0x7FFFu + ((u >> 16) & 1u);   // round-to-nearest-even
  return (u16)(u >> 16);
}

// ---------------- LayerNorm: fp32 [rows][1024] -> bf16 [rows][1024] --------
__global__ __launch_bounds__(256) void ln_k(const float* __restrict__ x,
                                            const float* __restrict__ g,
                                            const float* __restrict__ be,
                                            u16* __restrict__ out) {
  const int row = blockIdx.x;
  const int t = threadIdx.x;
  const float4 v = ((const float4*)(x + (size_t)row * 1024))[t];
  float s = v.x + v.y + v.z + v.w;
  float s2 = v.x * v.x + v.y * v.y + v.z * v.z + v.w * v.w;
#pragma unroll
  for (int off = 32; off > 0; off >>= 1) {
    s += __shfl_down(s, off);
    s2 += __shfl_down(s2, off);
  }
  __shared__ float red[8];
  if ((t & 63) == 0) { red[t >> 6] = s; red[4 + (t >> 6)] = s2; }
  __syncthreads();
  const float ts = red[0] + red[1] + red[2] + red[3];
  const float ts2 = red[4] + red[5] + red[6] + red[7];
  const float mu = ts * (1.0f / 1024.0f);
  const float var = ts2 * (1.0f / 1024.0f) - mu * mu;
  const float rstd = rsqrtf(var + 1e-5f);
  const float4 gv = ((const float4*)g)[t];
  const float4 bv = ((const float4*)be)[t];
  u16* op = out + (size_t)row * 1024 + t * 4;
  op[0] = f2bf((v.x - mu) * rstd * gv.x + bv.x);
  op[1] = f2bf((v.y - mu) * rstd * gv.y + bv.y);
  op[2] = f2bf((v.z - mu) * rstd * gv.z + bv.z);
  op[3] = f2bf((v.w - mu) * rstd * gv.w + bv.w);
}

// ------------- batched transpose fp32 [b][R][C] -> bf16 [b][C][R] ----------
__global__ __launch_bounds__(256) void transpose_k(const float* __restrict__ in,
                                                   u16* __restrict__ out,
                                                   int R, int Cc) {
  __shared__ float tile[32][33];
  const size_t base = (size_t)blockIdx.z * R * Cc;
  const int r0 = blockIdx.x * 32, c0 = blockIdx.y * 32;
  const int tx = threadIdx.x & 31, ty = threadIdx.x >> 5;
  const float* ip = in + base;
  u16* op = out + base;
#pragma unroll
  for (int i = 0; i < 32; i += 8)
    tile[ty + i][tx] = ip[(size_t)(r0 + ty + i) * Cc + c0 + tx];
  __syncthreads();
#pragma unroll
  for (int i = 0; i < 32; i += 8)
    op[(size_t)(c0 + ty + i) * R + r0 + tx] = f2bf(tile[tx][ty + i]);
}

// ---------------- GEMM: C[M][N] = A[M][K] * Bt[N][K]^T, epilogues ----------
// MODE 0: scatter to q[B,H,T,64], k[B,H,T,64], v_t[B,H,64,T] (bf16)
// MODE 1: out0(f32) = acc + bias[n] + resid[m][n]      (Wo proj + residual)
// MODE 2: out0(bf16) = relu(acc + bias[n])             (MLP up)
// MODE 3: out0(f32) = acc + bias[n] + resid[m][n]      (MLP down + residual)
template <int MODE>
__global__ __launch_bounds__(256, 2) void gemm_k(
    const u16* __restrict__ A, const u16* __restrict__ Bt,
    const float* __restrict__ bias, const float* __restrict__ resid,
    void* __restrict__ out0, void* __restrict__ out1, void* __restrict__ out2,
    int M, int N, int K) {
  __shared__ u16 As[128 * 40];   // +8 pad: 20-dword row stride -> 2-way bank alias (free)
  __shared__ u16 Bs[128 * 40];
  const int tid = threadIdx.x;
  const int lane = tid & 63;
  const int w = tid >> 6;
  const int wm = w & 1, wn = w >> 1;        // 2x2 wave grid, 64x64 per wave
  const int l15 = lane & 15, lq = lane >> 4;
  const int m0 = blockIdx.x * 128, n0 = blockIdx.y * 128;
  const int sr = tid >> 2;                   // staging row 0..63
  const int sc = (tid & 3) * 8;              // staging col 0,8,16,24

  f32x4 acc[4][4] = {};

  const size_t aoff0 = (size_t)(m0 + sr) * K + sc;
  const size_t aoff1 = (size_t)(m0 + 64 + sr) * K + sc;
  const size_t boff0 = (size_t)(n0 + sr) * K + sc;
  const size_t boff1 = (size_t)(n0 + 64 + sr) * K + sc;

  for (int k0 = 0; k0 < K; k0 += 32) {
    __syncthreads();
    *(int4*)&As[sr * 40 + sc]        = *(const int4*)&A[aoff0 + k0];
    *(int4*)&As[(64 + sr) * 40 + sc] = *(const int4*)&A[aoff1 + k0];
    *(int4*)&Bs[sr * 40 + sc]        = *(const int4*)&Bt[boff0 + k0];
    *(int4*)&Bs[(64 + sr) * 40 + sc] = *(const int4*)&Bt[boff1 + k0];
    __syncthreads();
    bf16x8 af[4], bfr[4];
#pragma unroll
    for (int i = 0; i < 4; ++i)
      af[i] = *(const bf16x8*)&As[(wm * 64 + i * 16 + l15) * 40 + lq * 8];
#pragma unroll
    for (int j = 0; j < 4; ++j)
      bfr[j] = *(const bf16x8*)&Bs[(wn * 64 + j * 16 + l15) * 40 + lq * 8];
#pragma unroll
    for (int i = 0; i < 4; ++i)
#pragma unroll
      for (int j = 0; j < 4; ++j)
        acc[i][j] = __builtin_amdgcn_mfma_f32_16x16x32_bf16(af[i], bfr[j], acc[i][j], 0, 0, 0);
  }

#pragma unroll
  for (int i = 0; i < 4; ++i) {
    const int mbase = m0 + wm * 64 + i * 16 + lq * 4;   // C/D row = lq*4+r
#pragma unroll
    for (int j = 0; j < 4; ++j) {
      const int ncol = n0 + wn * 64 + j * 16 + l15;     // C/D col = l15
#pragma unroll
      for (int r = 0; r < 4; ++r) {
        const float v = acc[i][j][r];
        const int m = mbase + r;
        if (MODE == 0) {
          const int which = ncol >> 10;
          const int hh = (ncol >> 6) & 15;
          const int dd = ncol & 63;
          const int bb = m >> 11;
          const int tt = m & 2047;
          const u16 val = f2bf(v);
          if (which == 0)
            ((u16*)out0)[(((size_t)(bb * 16 + hh) * 2048 + tt) << 6) + dd] = val;
          else if (which == 1)
            ((u16*)out1)[(((size_t)(bb * 16 + hh) * 2048 + tt) << 6) + dd] = val;
          else
            ((u16*)out2)[((size_t)(bb * 16 + hh) * 64 + dd) * 2048 + tt] = val;
        } else if (MODE == 1 || MODE == 3) {
          ((float*)out0)[(size_t)m * N + ncol] =
              v + bias[ncol] + resid[(size_t)m * N + ncol];
        } else {
          const float t2 = v + bias[ncol];
          ((u16*)out0)[(size_t)m * N + ncol] = f2bf(t2 > 0.0f ? t2 : 0.0f);
        }
      }
    }
  }
}

// ---------------- causal flash attention ------------------------------------
// q,k: [BH][2048][64] bf16; vt: [BH][64][2048] bf16 (V transposed)
// out attn: [B][2048][1024] bf16 (heads concatenated)
// Block: one (bh, 64-row Q tile); 4 waves, 16 Q rows each; KV tiles of 64.
__global__ __launch_bounds__(256) void flash_k(const u16* __restrict__ q,
                                               const u16* __restrict__ k,
                                               const u16* __restrict__ vt,
                                               u16* __restrict__ attn) {
  __shared__ u16 Qs[64 * 72];   // +8 pad rows
  __shared__ u16 Ks[64 * 72];
  __shared__ u16 Vs[64 * 72];   // V^T tile: row=d, col=j
  __shared__ u16 Ps[64 * 72];   // P in A-operand layout
  const int qblk = blockIdx.x;
  const int bh = blockIdx.y;
  const int bb = bh >> 4, hh = bh & 15;
  const int q0 = qblk * 64;
  const int tid = threadIdx.x;
  const int lane = tid & 63, wid = tid >> 6;
  const int l15 = lane & 15, lq = lane >> 4;

#pragma unroll
  for (int rep = 0; rep < 2; ++rep) {
    const int c = rep * 256 + tid;
    const int row = c >> 3, col = (c & 7) * 8;
    *(int4*)&Qs[row * 72 + col] =
        *(const int4*)&q[((size_t)bh * 2048 + q0 + row) * 64 + col];
  }

  f32x4 o[4] = {};
  float m_i[4], l_i[4];
#pragma unroll
  for (int r = 0; r < 4; ++r) { m_i[r] = -1e30f; l_i[r] = 0.0f; }

  const int i_base = q0 + wid * 16 + lq * 4;

  for (int j0 = 0; j0 < q0 + 64; j0 += 64) {
    __syncthreads();   // prev iteration's reads of Ks/Vs done (also covers Qs stage)
#pragma unroll
    for (int rep = 0; rep < 2; ++rep) {
      const int c = rep * 256 + tid;
      const int row = c >> 3, col = (c & 7) * 8;
      *(int4*)&Ks[row * 72 + col] =
          *(const int4*)&k[((size_t)bh * 2048 + j0 + row) * 64 + col];
      *(int4*)&Vs[row * 72 + col] =
          *(const int4*)&vt[((size_t)bh * 64 + row) * 2048 + j0 + col];
    }
    __syncthreads();

    // S = Q K^T for this wave's 16 rows x 64 cols
    f32x4 s[4] = {};
#pragma unroll
    for (int kk = 0; kk < 2; ++kk) {
      const bf16x8 a = *(const bf16x8*)&Qs[(wid * 16 + l15) * 72 + kk * 32 + lq * 8];
#pragma unroll
      for (int nt = 0; nt < 4; ++nt) {
        const bf16x8 bfr = *(const bf16x8*)&Ks[(nt * 16 + l15) * 72 + kk * 32 + lq * 8];
        s[nt] = __builtin_amdgcn_mfma_f32_16x16x32_bf16(a, bfr, s[nt], 0, 0, 0);
      }
    }

    // online softmax (per C/D row r; row stats reduced over the 16 col-lanes)
#pragma unroll
    for (int r = 0; r < 4; ++r) {
      float mx = -1e30f;
#pragma unroll
      for (int nt = 0; nt < 4; ++nt) {
        float vsc = s[nt][r] * 0.125f;                       // 1/sqrt(64)
        if (j0 + nt * 16 + l15 > i_base + r) vsc = -1e30f;   // causal mask
        s[nt][r] = vsc;
        mx = fmaxf(mx, vsc);
      }
#pragma unroll
      for (int off = 1; off < 16; off <<= 1) mx = fmaxf(mx, __shfl_xor(mx, off));
      const float nm = fmaxf(m_i[r], mx);
      const float alpha = __expf(m_i[r] - nm);
      m_i[r] = nm;
      float rs = 0.0f;
#pragma unroll
      for (int nt = 0; nt < 4; ++nt) {
        const float pv = __expf(s[nt][r] - nm);
        s[nt][r] = pv;
        rs += pv;
      }
#pragma unroll
      for (int off = 1; off < 16; off <<= 1) rs += __shfl_xor(rs, off);
      l_i[r] = l_i[r] * alpha + rs;
#pragma unroll
      for (int dt = 0; dt < 4; ++dt) o[dt][r] *= alpha;
    }

    // C/D layout -> A-operand layout via LDS
#pragma unroll
    for (int nt = 0; nt < 4; ++nt)
#pragma unroll
      for (int r = 0; r < 4; ++r)
        Ps[(wid * 16 + lq * 4 + r) * 72 + nt * 16 + l15] = f2bf(s[nt][r]);
    __syncthreads();

    // O += P V
#pragma unroll
    for (int kk = 0; kk < 2; ++kk) {
      const bf16x8 a = *(const bf16x8*)&Ps[(wid * 16 + l15) * 72 + kk * 32 + lq * 8];
#pragma unroll
      for (int dt = 0; dt < 4; ++dt) {
        const bf16x8 bfr = *(const bf16x8*)&Vs[(dt * 16 + l15) * 72 + kk * 32 + lq * 8];
        o[dt] = __builtin_amdgcn_mfma_f32_16x16x32_bf16(a, bfr, o[dt], 0, 0, 0);
      }
    }
  }

#pragma unroll
  for (int dt = 0; dt < 4; ++dt)
#pragma unroll
    for (int r = 0; r < 4; ++r) {
      const int i = i_base + r;
      attn[((size_t)bb * 2048 + i) * 1024 + hh * 64 + dt * 16 + l15] =
          f2bf(o[dt][r] / l_i[r]);
    }
}

// ---------------------------------------------------------------------------
extern "C" void kernel_launch(void* const* d_in, const int* in_sizes, int n_in,
                              void* d_out, int out_size, void* d_ws, size_t ws_size,
                              hipStream_t stream) {
  const float* x   = (const float*)d_in[0];
  const float* Wq  = (const float*)d_in[1];
  const float* Wk  = (const float*)d_in[2];
  const float* Wv  = (const float*)d_in[3];
  const float* Wo  = (const float*)d_in[4];
  const float* bo  = (const float*)d_in[5];
  const float* W1  = (const float*)d_in[6];
  const float* b1  = (const float*)d_in[7];
  const float* W2  = (const float*)d_in[8];
  const float* b2  = (const float*)d_in[9];
  const float* g1  = (const float*)d_in[10];
  const float* be1 = (const float*)d_in[11];
  const float* g2  = (const float*)d_in[12];
  const float* be2 = (const float*)d_in[13];
  float* out = (float*)d_out;

  char* ws = (char*)d_ws;
  u16* Wqkv_t = (u16*)(ws + 0);            //  6 MiB  [3072][1024]
  u16* Wo_t   = (u16*)(ws + 6291456);      //  2 MiB  [1024][1024]
  u16* W1_t   = (u16*)(ws + 8388608);      //  8 MiB  [4096][1024]
  u16* W2_t   = (u16*)(ws + 16777216);     //  8 MiB  [1024][4096]
  u16* hbuf   = (u16*)(ws + 25165824);     // 16 MiB  [8192][1024] (LN out, reused)
  float* x2   = (float*)(ws + 41943040);   // 32 MiB  [8192][1024] f32 mid residual
  u16* qb     = (u16*)(ws + 75497472);     // 16 MiB  [64][2048][64]
  u16* kb     = (u16*)(ws + 92274688);     // 16 MiB
  u16* vtb    = (u16*)(ws + 109051904);    // 16 MiB  [64][64][2048]
  u16* attnb  = (u16*)(ws + 125829120);    // 16 MiB  [8192][1024]
  u16* a1     = (u16*)(ws + 75497472);     // 64 MiB  [8192][4096], reuses q/k/vt/attn

  dim3 blk(256);

  // weights -> bf16, transposed to [N][K]
  transpose_k<<<dim3(32, 2, 16),  blk, 0, stream>>>(Wq, Wqkv_t,            1024, 64);
  transpose_k<<<dim3(32, 2, 16),  blk, 0, stream>>>(Wk, Wqkv_t + 1048576,  1024, 64);
  transpose_k<<<dim3(32, 2, 16),  blk, 0, stream>>>(Wv, Wqkv_t + 2097152,  1024, 64);
  transpose_k<<<dim3(32, 32, 1),  blk, 0, stream>>>(Wo, Wo_t,              1024, 1024);
  transpose_k<<<dim3(32, 128, 1), blk, 0, stream>>>(W1, W1_t,              1024, 4096);
  transpose_k<<<dim3(128, 32, 1), blk, 0, stream>>>(W2, W2_t,              4096, 1024);

  // LN1
  ln_k<<<8192, blk, 0, stream>>>(x, g1, be1, hbuf);
  // QKV projection with scatter epilogue
  gemm_k<0><<<dim3(64, 24), blk, 0, stream>>>(hbuf, Wqkv_t, nullptr, nullptr,
                                              qb, kb, vtb, 8192, 3072, 1024);
  // causal flash attention
  flash_k<<<dim3(32, 64), blk, 0, stream>>>(qb, kb, vtb, attnb);
  // output projection + bias + residual -> x2 (f32)
  gemm_k<1><<<dim3(64, 8), blk, 0, stream>>>(attnb, Wo_t, bo, x,
                                             x2, nullptr, nullptr, 8192, 1024, 1024);
  // LN2
  ln_k<<<8192, blk, 0, stream>>>(x2, g2, be2, hbuf);
  // MLP up + relu
  gemm_k<2><<<dim3(64, 32), blk, 0, stream>>>(hbuf, W1_t, b1, nullptr,
                                              a1, nullptr, nullptr, 8192, 4096, 1024);
  // MLP down + bias + residual -> out (f32)
  gemm_k<3><<<dim3(64, 8), blk, 0, stream>>>(a1, W2_t, b2, x2,
                                             out, nullptr, nullptr, 8192, 1024, 4096);
}

// Round 2
// 683.440 us; speedup vs baseline: 1.0184x; 1.0184x over previous
//
#include <hip/hip_runtime.h>
#include <cstdint>
#include <cstddef>

// ---------------------------------------------------------------------------
// Transformer block, MI355X bf16 MFMA implementation.
// R2: m97-style async global_load_lds GEMM staging; flash rewritten for
// occupancy (Q in regs, K/V direct-from-L2, LDS = P only, exp2 domain).
// ---------------------------------------------------------------------------

typedef unsigned short u16;
typedef __attribute__((ext_vector_type(8))) __bf16 bf16x8;   // 4 VGPRs, MFMA A/B frag
typedef __attribute__((ext_vector_type(4))) float f32x4;     // MFMA C/D frag

#if defined(__has_builtin)
#if __has_builtin(__builtin_amdgcn_global_load_lds)
#define HAS_GLL 1
#endif
#if __has_builtin(__builtin_amdgcn_exp2f)
#define EXP2(x) __builtin_amdgcn_exp2f(x)
#endif
#endif
#ifndef EXP2
#define EXP2(x) exp2f(x)
#endif

// attention scale 1/sqrt(64) folded with log2(e) so softmax runs in exp2 domain
#define QSCALE 0.18033688011112042f

__device__ __forceinline__ u16 f2bf(float f) {
  union { float f; unsigned int u; } c; c.f = f;
  unsigned int u = c.u;
  u += 0x7FFFu + ((u >> 16) & 1u);   // round-to-nearest-even
  return (u16)(u >> 16);
}
__device__ __forceinline__ u16 f2bf_fast(float f) {   // round-half-up, 2 insts
  union { float f; unsigned int u; } c; c.f = f;
  return (u16)((c.u + 0x8000u) >> 16);
}

// async 16B/lane global->LDS stage; l must be wave-uniform, lane i lands at l+16*i
__device__ __forceinline__ void stage16(const u16* g, u16* l, int lane) {
#ifdef HAS_GLL
  __builtin_amdgcn_global_load_lds(
      (const __attribute__((address_space(1))) uint32_t*)(g),
      (__attribute__((address_space(3))) uint32_t*)(l), 16, 0, 0);
#else
  *(int4*)(l + lane * 8) = *(const int4*)g;
#endif
}

// ---------------- LayerNorm: fp32 [rows][1024] -> bf16 [rows][1024] --------
__global__ __launch_bounds__(256) void ln_k(const float* __restrict__ x,
                                            const float* __restrict__ g,
                                            const float* __restrict__ be,
                                            u16* __restrict__ out) {
  const int row = blockIdx.x;
  const int t = threadIdx.x;
  const float4 v = ((const float4*)(x + (size_t)row * 1024))[t];
  float s = v.x + v.y + v.z + v.w;
  float s2 = v.x * v.x + v.y * v.y + v.z * v.z + v.w * v.w;
#pragma unroll
  for (int off = 32; off > 0; off >>= 1) {
    s += __shfl_down(s, off);
    s2 += __shfl_down(s2, off);
  }
  __shared__ float red[8];
  if ((t & 63) == 0) { red[t >> 6] = s; red[4 + (t >> 6)] = s2; }
  __syncthreads();
  const float ts = red[0] + red[1] + red[2] + red[3];
  const float ts2 = red[4] + red[5] + red[6] + red[7];
  const float mu = ts * (1.0f / 1024.0f);
  const float var = ts2 * (1.0f / 1024.0f) - mu * mu;
  const float rstd = rsqrtf(var + 1e-5f);
  const float4 gv = ((const float4*)g)[t];
  const float4 bv = ((const float4*)be)[t];
  u16* op = out + (size_t)row * 1024 + t * 4;
  op[0] = f2bf((v.x - mu) * rstd * gv.x + bv.x);
  op[1] = f2bf((v.y - mu) * rstd * gv.y + bv.y);
  op[2] = f2bf((v.z - mu) * rstd * gv.z + bv.z);
  op[3] = f2bf((v.w - mu) * rstd * gv.w + bv.w);
}

// ------------- batched transpose fp32 [b][R][C] -> bf16 [b][C][R] ----------
__global__ __launch_bounds__(256) void transpose_k(const float* __restrict__ in,
                                                   u16* __restrict__ out,
                                                   int R, int Cc) {
  __shared__ float tile[32][33];
  const size_t base = (size_t)blockIdx.z * R * Cc;
  const int r0 = blockIdx.x * 32, c0 = blockIdx.y * 32;
  const int tx = threadIdx.x & 31, ty = threadIdx.x >> 5;
  const float* ip = in + base;
  u16* op = out + base;
#pragma unroll
  for (int i = 0; i < 32; i += 8)
    tile[ty + i][tx] = ip[(size_t)(r0 + ty + i) * Cc + c0 + tx];
  __syncthreads();
#pragma unroll
  for (int i = 0; i < 32; i += 8)
    op[(size_t)(c0 + ty + i) * R + r0 + tx] = f2bf(tile[tx][ty + i]);
}

// ---------------- GEMM: C[M][N] = A[M][K] * Bt[N][K]^T, epilogues ----------
// MODE 0: scatter to q[B,H,T,64] (pre-scaled), k[B,H,T,64], v_t[B,H,64,T]
// MODE 1: out0(f32) = acc + bias[n] + resid[m][n]      (Wo proj + residual)
// MODE 2: out0(bf16) = relu(acc + bias[n])             (MLP up)
// MODE 3: out0(f32) = acc + bias[n] + resid[m][n]      (MLP down + residual)
template <int MODE>
__global__ __launch_bounds__(256, 2) void gemm_k(
    const u16* __restrict__ A, const u16* __restrict__ Bt,
    const float* __restrict__ bias, const float* __restrict__ resid,
    void* __restrict__ out0, void* __restrict__ out1, void* __restrict__ out2,
    int M, int N, int K) {
  __shared__ u16 As[128 * 32];   // unpadded: required by global_load_lds layout
  __shared__ u16 Bs[128 * 32];
  const int tid = threadIdx.x;
  const int lane = tid & 63;
  const int w = tid >> 6;
  const int wm = w & 1, wn = w >> 1;        // 2x2 wave grid, 64x64 per wave
  const int l15 = lane & 15, lq = lane >> 4;
  const int m0 = blockIdx.x * 128, n0 = blockIdx.y * 128;
  const int srow = lane >> 2, scol = (lane & 3) * 8;

  f32x4 acc[4][4] = {};

  // wave w stages As rows [w*32, w*32+32) and Bs rows [w*32, w*32+32)
  const u16* gA0 = A  + (size_t)(m0 + w * 32 + srow) * K + scol;
  const u16* gA1 = gA0 + (size_t)16 * K;
  const u16* gB0 = Bt + (size_t)(n0 + w * 32 + srow) * K + scol;
  const u16* gB1 = gB0 + (size_t)16 * K;
  u16* lA0 = &As[(w * 32) * 32];
  u16* lA1 = &As[(w * 32 + 16) * 32];
  u16* lB0 = &Bs[(w * 32) * 32];
  u16* lB1 = &Bs[(w * 32 + 16) * 32];

  for (int k0 = 0; k0 < K; k0 += 32) {
    __syncthreads();
    stage16(gA0 + k0, lA0, lane);
    stage16(gA1 + k0, lA1, lane);
    stage16(gB0 + k0, lB0, lane);
    stage16(gB1 + k0, lB1, lane);
    __syncthreads();   // drains vmcnt: staged data visible
    bf16x8 af[4], bfr[4];
#pragma unroll
    for (int i = 0; i < 4; ++i)
      af[i] = *(const bf16x8*)&As[(wm * 64 + i * 16 + l15) * 32 + lq * 8];
#pragma unroll
    for (int j = 0; j < 4; ++j)
      bfr[j] = *(const bf16x8*)&Bs[(wn * 64 + j * 16 + l15) * 32 + lq * 8];
#pragma unroll
    for (int i = 0; i < 4; ++i)
#pragma unroll
      for (int j = 0; j < 4; ++j)
        acc[i][j] = __builtin_amdgcn_mfma_f32_16x16x32_bf16(af[i], bfr[j], acc[i][j], 0, 0, 0);
  }

#pragma unroll
  for (int i = 0; i < 4; ++i) {
    const int mbase = m0 + wm * 64 + i * 16 + lq * 4;   // C/D row = lq*4+r
#pragma unroll
    for (int j = 0; j < 4; ++j) {
      const int ncol = n0 + wn * 64 + j * 16 + l15;     // C/D col = l15
#pragma unroll
      for (int r = 0; r < 4; ++r) {
        const float v = acc[i][j][r];
        const int m = mbase + r;
        if (MODE == 0) {
          const int which = ncol >> 10;
          const int hh = (ncol >> 6) & 15;
          const int dd = ncol & 63;
          const int bb = m >> 11;
          const int tt = m & 2047;
          if (which == 0)   // q: fold attention scale * log2(e)
            ((u16*)out0)[(((size_t)(bb * 16 + hh) * 2048 + tt) << 6) + dd] = f2bf(v * QSCALE);
          else if (which == 1)
            ((u16*)out1)[(((size_t)(bb * 16 + hh) * 2048 + tt) << 6) + dd] = f2bf(v);
          else
            ((u16*)out2)[((size_t)(bb * 16 + hh) * 64 + dd) * 2048 + tt] = f2bf(v);
        } else if (MODE == 1 || MODE == 3) {
          ((float*)out0)[(size_t)m * N + ncol] =
              v + bias[ncol] + resid[(size_t)m * N + ncol];
        } else {
          const float t2 = v + bias[ncol];
          ((u16*)out0)[(size_t)m * N + ncol] = f2bf(t2 > 0.0f ? t2 : 0.0f);
        }
      }
    }
  }
}

// ---------------- causal flash attention ------------------------------------
// q (pre-scaled by QSCALE), k: [BH][2048][64] bf16; vt: [BH][64][2048] bf16
// out attn: [B][2048][1024] bf16. Block = (bh, 64-row Q tile); 4 waves.
// Q fragments live in registers; K/V B-fragments read direct from global (L2:
// blockIdx.x = bh -> bh%8 XCD affinity -> 8 bh * 512KB = 4MB per XCD L2).
// LDS holds only the P (C/D->A layout) round-trip: 9 KB -> high occupancy.
__global__ __launch_bounds__(256) void flash_k(const u16* __restrict__ q,
                                               const u16* __restrict__ k,
                                               const u16* __restrict__ vt,
                                               u16* __restrict__ attn) {
  __shared__ u16 Ps[64 * 72];
  const int bh = blockIdx.x;
  const int qblk = 31 - blockIdx.y;          // longest blocks dispatch first
  const int q0 = qblk * 64;
  const int bb = bh >> 4, hh = bh & 15;
  const int tid = threadIdx.x;
  const int lane = tid & 63, wid = tid >> 6;
  const int l15 = lane & 15, lq = lane >> 4;

  // Q A-fragments in registers (rows wid*16+l15, K = 64 in two 32-chunks)
  const u16* qrow = q + ((size_t)bh * 2048 + q0 + wid * 16 + l15) * 64;
  const bf16x8 qa0 = *(const bf16x8*)&qrow[lq * 8];
  const bf16x8 qa1 = *(const bf16x8*)&qrow[32 + lq * 8];

  // K B-frag base: row l15 (+nt*16, +j), col lq*8 (+kk*32)
  const u16* kbase = k + ((size_t)bh * 2048 + l15) * 64 + lq * 8;
  // V^T B-frag base: row l15 (+dt*16) over d, col lq*8 (+j0+kk*32) over j
  const u16* vbase = vt + ((size_t)bh * 64 + l15) * 2048 + lq * 8;

  f32x4 o[4] = {};
  float m_i[4], l_i[4];
#pragma unroll
  for (int r = 0; r < 4; ++r) { m_i[r] = -1e30f; l_i[r] = 0.0f; }

  for (int it = 0; it <= qblk; ++it) {
    const int j0 = it * 64;
    // ---- S = Q K^T (already in exp2 domain via QSCALE) ----
    f32x4 s[4] = {};
#pragma unroll
    for (int kk = 0; kk < 2; ++kk) {
      const bf16x8 a = kk ? qa1 : qa0;
      const u16* kp = kbase + (size_t)j0 * 64 + kk * 32;
#pragma unroll
      for (int nt = 0; nt < 4; ++nt) {
        const bf16x8 bfr = *(const bf16x8*)(kp + nt * 1024);
        s[nt] = __builtin_amdgcn_mfma_f32_16x16x32_bf16(a, bfr, s[nt], 0, 0, 0);
      }
    }

    // ---- causal mask: only the diagonal tile needs it ----
    if (it == qblk) {
#pragma unroll
      for (int nt = 0; nt < 4; ++nt)
#pragma unroll
        for (int r = 0; r < 4; ++r)
          if (j0 + nt * 16 + l15 > q0 + wid * 16 + lq * 4 + r) s[nt][r] = -1e30f;
    }

    // ---- online softmax (exp2 domain) ----
#pragma unroll
    for (int r = 0; r < 4; ++r) {
      float mx = fmaxf(fmaxf(s[0][r], s[1][r]), fmaxf(s[2][r], s[3][r]));
#pragma unroll
      for (int off = 1; off < 16; off <<= 1) mx = fmaxf(mx, __shfl_xor(mx, off));
      const float nm = fmaxf(m_i[r], mx);
      const float alpha = EXP2(m_i[r] - nm);
      m_i[r] = nm;
      float rs = 0.0f;
#pragma unroll
      for (int nt = 0; nt < 4; ++nt) {
        const float pv = EXP2(s[nt][r] - nm);
        s[nt][r] = pv;
        rs += pv;
      }
#pragma unroll
      for (int off = 1; off < 16; off <<= 1) rs += __shfl_xor(rs, off);
      l_i[r] = l_i[r] * alpha + rs;
#pragma unroll
      for (int dt = 0; dt < 4; ++dt) o[dt][r] *= alpha;
    }

    // ---- P: C/D layout -> A-operand layout via LDS ----
    __syncthreads();   // prior PV reads of Ps complete
#pragma unroll
    for (int nt = 0; nt < 4; ++nt)
#pragma unroll
      for (int r = 0; r < 4; ++r)
        Ps[(wid * 16 + lq * 4 + r) * 72 + nt * 16 + l15] = f2bf_fast(s[nt][r]);
    __syncthreads();

    // ---- O += P V ----
#pragma unroll
    for (int kk = 0; kk < 2; ++kk) {
      const bf16x8 a = *(const bf16x8*)&Ps[(wid * 16 + l15) * 72 + kk * 32 + lq * 8];
      const u16* vp = vbase + j0 + kk * 32;
#pragma unroll
      for (int dt = 0; dt < 4; ++dt) {
        const bf16x8 bfr = *(const bf16x8*)(vp + (size_t)dt * 32768);
        o[dt] = __builtin_amdgcn_mfma_f32_16x16x32_bf16(a, bfr, o[dt], 0, 0, 0);
      }
    }
  }

#pragma unroll
  for (int r = 0; r < 4; ++r) {
    const float rl = 1.0f / l_i[r];
    const int i = q0 + wid * 16 + lq * 4 + r;
#pragma unroll
    for (int dt = 0; dt < 4; ++dt)
      attn[((size_t)bb * 2048 + i) * 1024 + hh * 64 + dt * 16 + l15] =
          f2bf(o[dt][r] * rl);
  }
}

// ---------------------------------------------------------------------------
extern "C" void kernel_launch(void* const* d_in, const int* in_sizes, int n_in,
                              void* d_out, int out_size, void* d_ws, size_t ws_size,
                              hipStream_t stream) {
  const float* x   = (const float*)d_in[0];
  const float* Wq  = (const float*)d_in[1];
  const float* Wk  = (const float*)d_in[2];
  const float* Wv  = (const float*)d_in[3];
  const float* Wo  = (const float*)d_in[4];
  const float* bo  = (const float*)d_in[5];
  const float* W1  = (const float*)d_in[6];
  const float* b1  = (const float*)d_in[7];
  const float* W2  = (const float*)d_in[8];
  const float* b2  = (const float*)d_in[9];
  const float* g1  = (const float*)d_in[10];
  const float* be1 = (const float*)d_in[11];
  const float* g2  = (const float*)d_in[12];
  const float* be2 = (const float*)d_in[13];
  float* out = (float*)d_out;

  char* ws = (char*)d_ws;
  u16* Wqkv_t = (u16*)(ws + 0);            //  6 MiB  [3072][1024]
  u16* Wo_t   = (u16*)(ws + 6291456);      //  2 MiB  [1024][1024]
  u16* W1_t   = (u16*)(ws + 8388608);      //  8 MiB  [4096][1024]
  u16* W2_t   = (u16*)(ws + 16777216);     //  8 MiB  [1024][4096]
  u16* hbuf   = (u16*)(ws + 25165824);     // 16 MiB  [8192][1024] (LN out, reused)
  float* x2   = (float*)(ws + 41943040);   // 32 MiB  [8192][1024] f32 mid residual
  u16* qb     = (u16*)(ws + 75497472);     // 16 MiB  [64][2048][64]
  u16* kb     = (u16*)(ws + 92274688);     // 16 MiB
  u16* vtb    = (u16*)(ws + 109051904);    // 16 MiB  [64][64][2048]
  u16* attnb  = (u16*)(ws + 125829120);    // 16 MiB  [8192][1024]
  u16* a1     = (u16*)(ws + 75497472);     // 64 MiB  [8192][4096], reuses q/k/vt/attn

  dim3 blk(256);

  // weights -> bf16, transposed to [N][K]
  transpose_k<<<dim3(32, 2, 16),  blk, 0, stream>>>(Wq, Wqkv_t,            1024, 64);
  transpose_k<<<dim3(32, 2, 16),  blk, 0, stream>>>(Wk, Wqkv_t + 1048576,  1024, 64);
  transpose_k<<<dim3(32, 2, 16),  blk, 0, stream>>>(Wv, Wqkv_t + 2097152,  1024, 64);
  transpose_k<<<dim3(32, 32, 1),  blk, 0, stream>>>(Wo, Wo_t,              1024, 1024);
  transpose_k<<<dim3(32, 128, 1), blk, 0, stream>>>(W1, W1_t,              1024, 4096);
  transpose_k<<<dim3(128, 32, 1), blk, 0, stream>>>(W2, W2_t,              4096, 1024);

  // LN1
  ln_k<<<8192, blk, 0, stream>>>(x, g1, be1, hbuf);
  // QKV projection with scatter epilogue (q pre-scaled)
  gemm_k<0><<<dim3(64, 24), blk, 0, stream>>>(hbuf, Wqkv_t, nullptr, nullptr,
                                              qb, kb, vtb, 8192, 3072, 1024);
  // causal flash attention
  flash_k<<<dim3(64, 32), blk, 0, stream>>>(qb, kb, vtb, attnb);
  // output projection + bias + residual -> x2 (f32)
  gemm_k<1><<<dim3(64, 8), blk, 0, stream>>>(attnb, Wo_t, bo, x,
                                             x2, nullptr, nullptr, 8192, 1024, 1024);
  // LN2
  ln_k<<<8192, blk, 0, stream>>>(x2, g2, be2, hbuf);
  // MLP up + relu
  gemm_k<2><<<dim3(64, 32), blk, 0, stream>>>(hbuf, W1_t, b1, nullptr,
                                              a1, nullptr, nullptr, 8192, 4096, 1024);
  // MLP down + bias + residual -> out (f32)
  gemm_k<3><<<dim3(64, 8), blk, 0, stream>>>(a1, W2_t, b2, x2,
                                             out, nullptr, nullptr, 8192, 1024, 4096);
}